// Round 10
// baseline (2507.386 us; speedup 1.0000x reference)
//
#include <hip/hip_runtime.h>
#include <math.h>

#define S_DIM 4
#define F_DIM 1128
#define T_DIM 1000
#define D_DIM 13
#define SF_DIM (S_DIM * F_DIM)      // 4512
#define NSUM 104                     // 13 mean + 91 packed upper-tri m2

// packed index helpers
__device__ __forceinline__ constexpr int LIdx(int r, int c) { return r * (r + 1) / 2 + c; }           // lower, r>=c
__device__ __forceinline__ constexpr int UIdx(int i, int j) { return i * 13 - i * (i - 1) / 2 + (j - i); } // upper, i<=j

// ---------------------------------------------------------------------------
// Kernel 1 (v3): per-(s,f,tensor) sums over T frames.
// Round-9 counters: pair-split killed the spill (WRITE 286->3.7 MB, VGPR 76)
// but dur stayed 157us: Occupancy 28% (~9 waves/CU) + VALUBusy 29% -- latency
// bound, with the even/odd exec-masked split doubling FMA issue.
// v3: full acc[104] per lane, ONE frame (13 floats) per iteration =>
// demand ~= 104 + 13 + addr ~= 123 < 128 (no spill, no divergent doubling,
// no shuffle overhead in the hot loop). 4 waves per 256-thread block (each
// wave owns one sf task) to pack more waves per CU than the 1-wave-block
// dispatch achieved. __launch_bounds__(256,4) pins the 128-VGPR band.
// ---------------------------------------------------------------------------
__global__ __launch_bounds__(256, 4) void moments_kernel(const float* __restrict__ pv,
                                                         const float* __restrict__ qv,
                                                         float* __restrict__ sums) {
    const int l = threadIdx.x & 63;          // lane in wave
    const int wave = threadIdx.x >> 6;       // 0..3
    const int which = blockIdx.y;            // 0 = p, 1 = q
    const int sf = blockIdx.x * 4 + wave;    // 0..4511 (1128 blocks.x)

    const float* __restrict__ v = (which == 0 ? pv : qv) + (size_t)sf * (T_DIM * D_DIM);

    float acc[NSUM];
#pragma unroll
    for (int i = 0; i < NSUM; ++i) acc[i] = 0.0f;

    // frame f = l + 64*it, it = 0..15 (last round partial: lanes >= 40 idle)
#pragma unroll 1
    for (int it = 0; it < 16; ++it) {
        const int f = l + 64 * it;
        if (f < T_DIM) {
            const float* __restrict__ fr = v + (size_t)f * 13;
            float x[13];
#pragma unroll
            for (int i = 0; i < 13; ++i) x[i] = fr[i];
            int kk = 13;
#pragma unroll
            for (int i = 0; i < 13; ++i) {
                float xi = x[i];
                acc[i] += xi;
#pragma unroll
                for (int j = i; j < 13; ++j) {
                    acc[kk] += xi * x[j];
                    ++kk;
                }
            }
        }
    }

    // butterfly reduce across the full 64-lane wave
#pragma unroll
    for (int i = 0; i < NSUM; ++i) {
        acc[i] += __shfl_xor(acc[i], 1);
        acc[i] += __shfl_xor(acc[i], 2);
        acc[i] += __shfl_xor(acc[i], 4);
        acc[i] += __shfl_xor(acc[i], 8);
        acc[i] += __shfl_xor(acc[i], 16);
        acc[i] += __shfl_xor(acc[i], 32);
    }

    if (l == 0) {
        float* o = sums + ((size_t)which * SF_DIM + sf) * NSUM;
#pragma unroll
        for (int i = 0; i < NSUM; ++i) o[i] = acc[i];
    }
}

// ---------------------------------------------------------------------------
// Kernel 2 (v2): symmetric KL in fp64, matrices in LDS, p/q lane-split.
// Theory: old version demanded ~430 VGPRs of fp64 matrix state under an
// allocator that demonstrably clamps (round 4: 225->128) => likely scratch
// storm hidden below the top-5 cut (residue ~487us). v2: each 64-thread
// block handles 32 sf; lane l<32 owns Sigma_p for sf=blk*32+(l&31), lane
// l+32 owns Sigma_q for the same sf. Factor L lives in LDS column [*][l]
// ([91][64] doubles = 46.6 KB < 64 KB static limit); uniform row index per
// instruction => bank-optimal. Cross solves read the teammate's column
// (l^32); tr/quad combine via __shfl_xor(.,32). Each lane does HALF the old
// serial work; register demand ~90 (x[13]+d[13]+scalars). Same fp64 op
// sequence as before => numerics preserved.
// ---------------------------------------------------------------------------
__device__ __forceinline__ void chol13_lds(double (*A)[64], int l) {
#pragma unroll
    for (int c = 0; c < 13; ++c) {
        double dg = A[LIdx(c, c)][l];
#pragma unroll
        for (int t = 0; t < c; ++t) { double v = A[LIdx(c, t)][l]; dg -= v * v; }
        dg = sqrt(dg);
        A[LIdx(c, c)][l] = dg;
        double inv = 1.0 / dg;
#pragma unroll
        for (int r = c + 1; r < 13; ++r) {
            double s = A[LIdx(r, c)][l];
#pragma unroll
            for (int t = 0; t < c; ++t) s -= A[LIdx(r, t)][l] * A[LIdx(c, t)][l];
            A[LIdx(r, c)][l] = s * inv;
        }
    }
}

// || Lden^{-1} Lnum ||_F^2 ; Lden = column dl, Lnum = column nl
__device__ __forceinline__ double trsolve_fro2_lds(double (*A)[64], int dl, int nl) {
    double tr = 0.0;
#pragma unroll
    for (int j = 0; j < 13; ++j) {
        double x[13];
#pragma unroll
        for (int r = j; r < 13; ++r) {
            double s = A[LIdx(r, j)][nl];
#pragma unroll
            for (int t = j; t < r; ++t) s -= A[LIdx(r, t)][dl] * x[t];
            x[r] = s / A[LIdx(r, r)][dl];
            tr += x[r] * x[r];
        }
    }
    return tr;
}

// d^T (L L^T)^{-1} d with L = column dl
__device__ __forceinline__ double quadsolve_lds(double (*A)[64], int dl, const double* d) {
    double x[13];
    double q = 0.0;
#pragma unroll
    for (int r = 0; r < 13; ++r) {
        double s = d[r];
#pragma unroll
        for (int t = 0; t < r; ++t) s -= A[LIdx(r, t)][dl] * x[t];
        x[r] = s / A[LIdx(r, r)][dl];
        q += x[r] * x[r];
    }
    return q;
}

__global__ __launch_bounds__(64, 1) void kl_kernel(const float* __restrict__ sums,
                                                   const float* __restrict__ plen,
                                                   const float* __restrict__ qlen,
                                                   const float* __restrict__ mask,
                                                   float* __restrict__ feats) {
    __shared__ double Ls[91][64];
    const int l = threadIdx.x;           // 0..63
    const int half = l >> 5;             // 0 = p-side, 1 = q-side
    const int j = l & 31;
    const int sf = blockIdx.x * 32 + j;  // 141 blocks * 32 = 4512 exactly

    const float* __restrict__ ms = sums + ((size_t)half * SF_DIM + sf) * NSUM;
    const double len = (double)(half ? qlen[sf] : plen[sf]);

    double m[13];
#pragma unroll
    for (int i = 0; i < 13; ++i) m[i] = (double)ms[i] / len;

    // build own covariance factor input in own LDS column
#pragma unroll
    for (int r = 0; r < 13; ++r) {
#pragma unroll
        for (int c = 0; c <= r; ++c) {
            double ep = (r == c) ? 1e-3 : 0.0;
            Ls[LIdx(r, c)][l] = (double)ms[13 + UIdx(c, r)] / len - m[c] * m[r] + ep;
        }
    }

    chol13_lds(Ls, l);
    __syncthreads();                      // memory-ordering fence (single wave)

    const int tl = l ^ 32;               // teammate's column

    // d = m_own - m_other (sign-symmetric: only squares of L^{-1} d are used)
    double d[13];
#pragma unroll
    for (int i = 0; i < 13; ++i) {
        double mo = __shfl_xor(m[i], 32);
        d[i] = m[i] - mo;
    }

    // each lane: || L_teammate^{-1} L_own ||_F^2  and  d^T Sigma_teammate^{-1} d
    double tr = trsolve_fro2_lds(Ls, tl, l);
    double quad = quadsolve_lds(Ls, tl, d);

    double tot_tr = tr + __shfl_xor(tr, 32);
    double tot_q  = quad + __shfl_xor(quad, 32);

    if (half == 0) {
        double kl = 0.25 * (tot_tr + tot_q - 2.0 * 13.0);
        double ft = log(kl + 1e-5);
        double mk = (double)mask[sf];
        feats[sf] = (float)((ft + 1.0) * mk - 1.0);
    }
}

// ---------------------------------------------------------------------------
// MLP: split-K partial GEMV per layer. Each block owns an i-chunk; staging
// reduces the PREVIOUS layer's partials (+bias+ReLU), or applies BatchNorm to
// feats for layer 1. Staging is parallelized over (idx, s) pairs: 4*clen
// threads each sum prev_ns partials. Compute: each lane owns 4 output
// columns (float4 W loads).  [unchanged — no counters on these yet]
// ---------------------------------------------------------------------------
__global__ __launch_bounds__(256) void layer_partial(const float* __restrict__ W,
                                                     const int in_dim, const int out_dim,
                                                     const int chunk,
                                                     const float* __restrict__ prev_part,
                                                     const int prev_ns,
                                                     const float* __restrict__ prev_bias,
                                                     const float* __restrict__ feats,
                                                     const float* __restrict__ gamma,
                                                     const float* __restrict__ beta,
                                                     float* __restrict__ out_part) {
    __shared__ float hlds[4][48];
    const int p = blockIdx.x;
    const int i0 = p * chunk;
    const int clen = min(chunk, in_dim - i0);
    const int tid = threadIdx.x;

    if (feats != nullptr) {
        // layer 1: BatchNorm(feats) staged into LDS
        if (tid < clen) {
            const int f = i0 + tid;
            float v0 = feats[f];
            float v1 = feats[F_DIM + f];
            float v2 = feats[2 * F_DIM + f];
            float v3 = feats[3 * F_DIM + f];
            float mu = 0.25f * (v0 + v1 + v2 + v3);
            float d0 = v0 - mu, d1 = v1 - mu, d2 = v2 - mu, d3 = v3 - mu;
            float var = 0.25f * (d0 * d0 + d1 * d1 + d2 * d2 + d3 * d3);
            float inv = 1.0f / sqrtf(var + 1e-5f);
            float ga = gamma[f], be = beta[f];
            hlds[0][tid] = d0 * inv * ga + be;
            hlds[1][tid] = d1 * inv * ga + be;
            hlds[2][tid] = d2 * inv * ga + be;
            hlds[3][tid] = d3 * inv * ga + be;
        }
    } else {
        // middle layers: reduce prev partials + bias + relu.
        const int idx = tid >> 2;
        const int s = tid & 3;
        if (idx < clen) {
            const int i = i0 + idx;
            float a = prev_bias[i];
            for (int pp = 0; pp < prev_ns; ++pp) {
                a += prev_part[((size_t)pp * 4 + s) * in_dim + i];
            }
            hlds[s][idx] = fmaxf(a, 0.0f);
        }
    }
    __syncthreads();

    const int j4 = tid * 4;
    if (j4 < out_dim) {
        float acc[4][4] = {{0.f, 0.f, 0.f, 0.f}, {0.f, 0.f, 0.f, 0.f},
                           {0.f, 0.f, 0.f, 0.f}, {0.f, 0.f, 0.f, 0.f}};
        for (int idx = 0; idx < clen; ++idx) {
            float4 w = *(const float4*)(W + (size_t)(i0 + idx) * out_dim + j4);
#pragma unroll
            for (int s = 0; s < 4; ++s) {
                float h = hlds[s][idx];
                acc[s][0] += h * w.x;
                acc[s][1] += h * w.y;
                acc[s][2] += h * w.z;
                acc[s][3] += h * w.w;
            }
        }
#pragma unroll
        for (int s = 0; s < 4; ++s) {
            float4 o = make_float4(acc[s][0], acc[s][1], acc[s][2], acc[s][3]);
            *(float4*)(out_part + ((size_t)p * 4 + s) * out_dim + j4) = o;
        }
    }
}

// Layer 7 (1000 -> 1): per-block partial dot over an i-chunk.
__global__ __launch_bounds__(256) void layer7_partial(const float* __restrict__ W7,
                                                      const float* __restrict__ part6,
                                                      const float* __restrict__ b6,
                                                      float* __restrict__ part7,
                                                      const int in_dim, const int chunk,
                                                      const int prev_ns) {
    __shared__ float hl[4][32];
    __shared__ float wl[32];
    const int p = blockIdx.x;
    const int i0 = p * chunk;
    const int clen = min(chunk, in_dim - i0);
    const int tid = threadIdx.x;

    {
        const int idx = tid >> 2;
        const int s = tid & 3;
        if (idx < clen) {
            const int i = i0 + idx;
            float a = b6[i];
            for (int pp = 0; pp < prev_ns; ++pp) {
                a += part6[((size_t)pp * 4 + s) * in_dim + i];
            }
            hl[s][idx] = fmaxf(a, 0.0f);
            if (s == 0) wl[idx] = W7[i];
        }
    }
    __syncthreads();

    if (tid < 4) {
        float acc = 0.0f;
        for (int idx = 0; idx < clen; ++idx) acc += hl[tid][idx] * wl[idx];
        part7[p * 4 + tid] = acc;
    }
}

__global__ void final_kernel(const float* __restrict__ part7,
                             const float* __restrict__ b7,
                             float* __restrict__ out, const int ns) {
    const int s = threadIdx.x;
    if (s < 4) {
        float acc = b7[0];
        for (int p = 0; p < ns; ++p) acc += part7[p * 4 + s];
        out[s] = acc;
    }
}

// ---------------------------------------------------------------------------
extern "C" void kernel_launch(void* const* d_in, const int* in_sizes, int n_in,
                              void* d_out, int out_size, void* d_ws, size_t ws_size,
                              hipStream_t stream) {
    const float* pv    = (const float*)d_in[0];
    const float* qv    = (const float*)d_in[1];
    const float* plen  = (const float*)d_in[2];
    const float* qlen  = (const float*)d_in[3];
    const float* mask  = (const float*)d_in[4];
    const float* gamma = (const float*)d_in[5];
    const float* beta  = (const float*)d_in[6];
    const float* W[7];
    const float* b[7];
    for (int i = 0; i < 7; ++i) {
        W[i] = (const float*)d_in[7 + 2 * i];
        b[i] = (const float*)d_in[8 + 2 * i];
    }

    float* ws = (float*)d_ws;
    float* sums  = ws;                                  // 2*4512*104 = 938496 floats
    float* feats = ws + 938496;                         // 4512 floats
    float* partA = ws + 943008;                         // 32*4*1000 = 128000 floats (16B-aligned)
    float* partB = partA + 128000;                      // 128000 floats
    float* part7 = partB + 128000;                      // 128 floats
    float* out = (float*)d_out;

    // 1) moments: 4 waves/block, one wave per (sf, tensor) task
    moments_kernel<<<dim3(1128, 2), 256, 0, stream>>>(pv, qv, sums);
    // 2) symmetric KL -> feats: 32 sf per block, p/q lane-split, LDS factors
    kl_kernel<<<dim3(141), 64, 0, stream>>>(sums, plen, qlen, mask, feats);
    // 3) MLP. L1 fuses BatchNorm; each layer fuses prev partial-reduce+bias+relu.
    layer_partial<<<32, 256, 0, stream>>>(W[0], 1128, 1000, 36, nullptr, 0, nullptr,
                                          feats, gamma, beta, partA);
    layer_partial<<<32, 256, 0, stream>>>(W[1], 1000, 1000, 32, partA, 32, b[0],
                                          nullptr, nullptr, nullptr, partB);
    layer_partial<<<32, 256, 0, stream>>>(W[2], 1000, 1000, 32, partB, 32, b[1],
                                          nullptr, nullptr, nullptr, partA);
    layer_partial<<<32, 256, 0, stream>>>(W[3], 1000, 1000, 32, partA, 32, b[2],
                                          nullptr, nullptr, nullptr, partB);
    layer_partial<<<32, 256, 0, stream>>>(W[4], 1000, 1000, 32, partB, 32, b[3],
                                          nullptr, nullptr, nullptr, partA);
    layer_partial<<<32, 256, 0, stream>>>(W[5], 1000, 1000, 32, partA, 32, b[4],
                                          nullptr, nullptr, nullptr, partB);
    layer7_partial<<<32, 256, 0, stream>>>(W[6], partB, b[5], part7, 1000, 32, 32);
    final_kernel<<<1, 64, 0, stream>>>(part7, b[6], out, 32);
}

// Round 13
// 577.568 us; speedup vs baseline: 4.3413x; 4.3413x over previous
//
#include <hip/hip_runtime.h>
#include <math.h>

#define S_DIM 4
#define F_DIM 1128
#define T_DIM 1000
#define D_DIM 13
#define SF_DIM (S_DIM * F_DIM)      // 4512
#define NSUM 104                     // 13 mean + 91 packed upper-tri m2

// packed index helpers
__device__ __forceinline__ constexpr int LIdx(int r, int c) { return r * (r + 1) / 2 + c; }           // lower, r>=c
__device__ __forceinline__ constexpr int UIdx(int i, int j) { return i * 13 - i * (i - 1) / 2 + (j - i); } // upper, i<=j

// ---------------------------------------------------------------------------
// Kernel 1 (v4): per-(s,f,tensor) sums. HOT LOOP IDENTICAL to the round-9
// pair-split version (measured: VGPR 76, zero spill, 157us) -- the ONLY
// change is packing 4 waves per 256-thread block (1128x2 blocks instead of
// 9024 1-wave blocks) to lift the 28% occupancy (~9 waves/CU, workgroup-
// slot-limited) toward ~24 waves/CU (VGPR-76 cap). Round-10 lesson (hard
// law): per-lane accumulator must stay <= ~52 floats; acc[104] spills
// catastrophically (VGPR 64, 5.6 GB scratch writes, 2034us).
// Pair-split: team = lane pair (2k,2k+1); each lane loads one frame-pair
// (26 floats, 8B-aligned float2); teammate's values via wave-uniform
// __shfl_xor(.,1); even lanes accumulate kk=0..51, odd kk=52..103; butterfly
// with parity-preserving masks; lanes 0/1 write the two 52-halves => sums
// layout identical to all prior rounds.
// ---------------------------------------------------------------------------
template<int LO, int HI>
__device__ __forceinline__ void accum_range(const float* __restrict__ x,
                                            float* __restrict__ acc) {
    int kk = 0;
#pragma unroll
    for (int i = 0; i < 13; ++i) {          // means: kk = 0..12
        if (kk >= LO && kk < HI) acc[kk - LO] += x[i];
        ++kk;
    }
#pragma unroll
    for (int i = 0; i < 13; ++i) {          // m2 upper-tri: kk = 13..103
#pragma unroll
        for (int j = i; j < 13; ++j) {
            if (kk >= LO && kk < HI) acc[kk - LO] += x[i] * x[j];
            ++kk;
        }
    }
}

__global__ __launch_bounds__(256) void moments_kernel(const float* __restrict__ pv,
                                                      const float* __restrict__ qv,
                                                      float* __restrict__ sums) {
    const int l = threadIdx.x & 63;          // lane in wave
    const int wave = threadIdx.x >> 6;       // 0..3
    const int which = blockIdx.y;            // 0 = p, 1 = q
    const int sf = blockIdx.x * 4 + wave;    // 0..4511 (1128 blocks.x)

    const float* __restrict__ v = (which == 0 ? pv : qv) + (size_t)sf * (T_DIM * D_DIM);

    float acc[52];
#pragma unroll
    for (int i = 0; i < 52; ++i) acc[i] = 0.0f;

    const bool odd = (l & 1);

    // 500 frame-pairs; lane l handles pair m = l, l+64, ... (8 rounds, last partial)
#pragma unroll 1
    for (int it = 0; it < 8; ++it) {
        const int m = l + 64 * it;       // frame-pair index
        float x[26];
        if (m < 500) {
            const float2* p2 = (const float2*)(v + (size_t)m * 26);  // 104*m bytes, 8B-aligned
#pragma unroll
            for (int i = 0; i < 13; ++i) {
                float2 t = p2[i];
                x[2 * i]     = t.x;
                x[2 * i + 1] = t.y;
            }
        } else {
#pragma unroll
            for (int i = 0; i < 26; ++i) x[i] = 0.0f;   // zero frames contribute nothing
        }

        // teammate's two frames (wave-uniform shuffles; never inside divergence)
        float y0[13], y1[13];
#pragma unroll
        for (int i = 0; i < 13; ++i) y0[i] = __shfl_xor(x[i], 1);
#pragma unroll
        for (int i = 0; i < 13; ++i) y1[i] = __shfl_xor(x[13 + i], 1);

        if (!odd) {
            accum_range<0, 52>(x, acc);        // own frame 2m
            accum_range<0, 52>(x + 13, acc);   // own frame 2m+1
            accum_range<0, 52>(y0, acc);       // teammate frame
            accum_range<0, 52>(y1, acc);       // teammate frame
        } else {
            accum_range<52, 104>(x, acc);
            accum_range<52, 104>(x + 13, acc);
            accum_range<52, 104>(y0, acc);
            accum_range<52, 104>(y1, acc);
        }
    }

    // butterfly reduce across same-parity lanes (masks keep parity classes)
#pragma unroll
    for (int i = 0; i < 52; ++i) {
        acc[i] += __shfl_xor(acc[i], 2);
        acc[i] += __shfl_xor(acc[i], 4);
        acc[i] += __shfl_xor(acc[i], 8);
        acc[i] += __shfl_xor(acc[i], 16);
        acc[i] += __shfl_xor(acc[i], 32);
    }

    if (l < 2) {
        float* o = sums + ((size_t)which * SF_DIM + sf) * NSUM + (size_t)l * 52;
#pragma unroll
        for (int i = 0; i < 52; ++i) o[i] = acc[i];
    }
}

// ---------------------------------------------------------------------------
// Kernel 2 (v2, harness-verified round 10): symmetric KL in fp64, factors in
// LDS, p/q lane-split. Each 64-thread block handles 32 sf; lane l<32 owns
// Sigma_p, lane l+32 owns Sigma_q for the same sf; cross-solves read the
// teammate's LDS column; combine via __shfl_xor(.,32).
// ---------------------------------------------------------------------------
__device__ __forceinline__ void chol13_lds(double (*A)[64], int l) {
#pragma unroll
    for (int c = 0; c < 13; ++c) {
        double dg = A[LIdx(c, c)][l];
#pragma unroll
        for (int t = 0; t < c; ++t) { double v = A[LIdx(c, t)][l]; dg -= v * v; }
        dg = sqrt(dg);
        A[LIdx(c, c)][l] = dg;
        double inv = 1.0 / dg;
#pragma unroll
        for (int r = c + 1; r < 13; ++r) {
            double s = A[LIdx(r, c)][l];
#pragma unroll
            for (int t = 0; t < c; ++t) s -= A[LIdx(r, t)][l] * A[LIdx(c, t)][l];
            A[LIdx(r, c)][l] = s * inv;
        }
    }
}

// || Lden^{-1} Lnum ||_F^2 ; Lden = column dl, Lnum = column nl
__device__ __forceinline__ double trsolve_fro2_lds(double (*A)[64], int dl, int nl) {
    double tr = 0.0;
#pragma unroll
    for (int j = 0; j < 13; ++j) {
        double x[13];
#pragma unroll
        for (int r = j; r < 13; ++r) {
            double s = A[LIdx(r, j)][nl];
#pragma unroll
            for (int t = j; t < r; ++t) s -= A[LIdx(r, t)][dl] * x[t];
            x[r] = s / A[LIdx(r, r)][dl];
            tr += x[r] * x[r];
        }
    }
    return tr;
}

// d^T (L L^T)^{-1} d with L = column dl
__device__ __forceinline__ double quadsolve_lds(double (*A)[64], int dl, const double* d) {
    double x[13];
    double q = 0.0;
#pragma unroll
    for (int r = 0; r < 13; ++r) {
        double s = d[r];
#pragma unroll
        for (int t = 0; t < r; ++t) s -= A[LIdx(r, t)][dl] * x[t];
        x[r] = s / A[LIdx(r, r)][dl];
        q += x[r] * x[r];
    }
    return q;
}

__global__ __launch_bounds__(64, 1) void kl_kernel(const float* __restrict__ sums,
                                                   const float* __restrict__ plen,
                                                   const float* __restrict__ qlen,
                                                   const float* __restrict__ mask,
                                                   float* __restrict__ feats) {
    __shared__ double Ls[91][64];
    const int l = threadIdx.x;           // 0..63
    const int half = l >> 5;             // 0 = p-side, 1 = q-side
    const int j = l & 31;
    const int sf = blockIdx.x * 32 + j;  // 141 blocks * 32 = 4512 exactly

    const float* __restrict__ ms = sums + ((size_t)half * SF_DIM + sf) * NSUM;
    const double len = (double)(half ? qlen[sf] : plen[sf]);

    double m[13];
#pragma unroll
    for (int i = 0; i < 13; ++i) m[i] = (double)ms[i] / len;

    // build own covariance factor input in own LDS column
#pragma unroll
    for (int r = 0; r < 13; ++r) {
#pragma unroll
        for (int c = 0; c <= r; ++c) {
            double ep = (r == c) ? 1e-3 : 0.0;
            Ls[LIdx(r, c)][l] = (double)ms[13 + UIdx(c, r)] / len - m[c] * m[r] + ep;
        }
    }

    chol13_lds(Ls, l);
    __syncthreads();                      // memory-ordering fence (single wave)

    const int tl = l ^ 32;               // teammate's column

    // d = m_own - m_other (sign-symmetric: only squares of L^{-1} d are used)
    double d[13];
#pragma unroll
    for (int i = 0; i < 13; ++i) {
        double mo = __shfl_xor(m[i], 32);
        d[i] = m[i] - mo;
    }

    // each lane: || L_teammate^{-1} L_own ||_F^2  and  d^T Sigma_teammate^{-1} d
    double tr = trsolve_fro2_lds(Ls, tl, l);
    double quad = quadsolve_lds(Ls, tl, d);

    double tot_tr = tr + __shfl_xor(tr, 32);
    double tot_q  = quad + __shfl_xor(quad, 32);

    if (half == 0) {
        double kl = 0.25 * (tot_tr + tot_q - 2.0 * 13.0);
        double ft = log(kl + 1e-5);
        double mk = (double)mask[sf];
        feats[sf] = (float)((ft + 1.0) * mk - 1.0);
    }
}

// ---------------------------------------------------------------------------
// MLP: split-K partial GEMV per layer. Residue theory: these 9 dispatches own
// the stable ~470-490us residue, latency-bound (32 CUs, serial load->FMA
// chains). Fix: batch-8 unrolled loads in BOTH the staging reduce (32 -> 4
// serial latency exposures) and the compute loop (32 -> 4). Same grid,
// layout, workspace.
// ---------------------------------------------------------------------------
__global__ __launch_bounds__(256) void layer_partial(const float* __restrict__ W,
                                                     const int in_dim, const int out_dim,
                                                     const int chunk,
                                                     const float* __restrict__ prev_part,
                                                     const int prev_ns,
                                                     const float* __restrict__ prev_bias,
                                                     const float* __restrict__ feats,
                                                     const float* __restrict__ gamma,
                                                     const float* __restrict__ beta,
                                                     float* __restrict__ out_part) {
    __shared__ float hlds[4][48];
    const int p = blockIdx.x;
    const int i0 = p * chunk;
    const int clen = min(chunk, in_dim - i0);
    const int tid = threadIdx.x;

    if (feats != nullptr) {
        // layer 1: BatchNorm(feats) staged into LDS
        if (tid < clen) {
            const int f = i0 + tid;
            float v0 = feats[f];
            float v1 = feats[F_DIM + f];
            float v2 = feats[2 * F_DIM + f];
            float v3 = feats[3 * F_DIM + f];
            float mu = 0.25f * (v0 + v1 + v2 + v3);
            float d0 = v0 - mu, d1 = v1 - mu, d2 = v2 - mu, d3 = v3 - mu;
            float var = 0.25f * (d0 * d0 + d1 * d1 + d2 * d2 + d3 * d3);
            float inv = 1.0f / sqrtf(var + 1e-5f);
            float ga = gamma[f], be = beta[f];
            hlds[0][tid] = d0 * inv * ga + be;
            hlds[1][tid] = d1 * inv * ga + be;
            hlds[2][tid] = d2 * inv * ga + be;
            hlds[3][tid] = d3 * inv * ga + be;
        }
    } else {
        // middle layers: reduce prev partials + bias + relu, (idx,s) remap,
        // batch-8 loads for ILP.
        const int idx = tid >> 2;
        const int s = tid & 3;
        if (idx < clen) {
            const int i = i0 + idx;
            float a = prev_bias[i];
            int pp0 = 0;
            for (; pp0 + 8 <= prev_ns; pp0 += 8) {
                float t[8];
#pragma unroll
                for (int k = 0; k < 8; ++k)
                    t[k] = prev_part[((size_t)(pp0 + k) * 4 + s) * in_dim + i];
#pragma unroll
                for (int k = 0; k < 8; ++k) a += t[k];
            }
            for (; pp0 < prev_ns; ++pp0)
                a += prev_part[((size_t)pp0 * 4 + s) * in_dim + i];
            hlds[s][idx] = fmaxf(a, 0.0f);
        }
    }
    __syncthreads();

    const int j4 = tid * 4;
    if (j4 < out_dim) {
        float acc[4][4] = {{0.f, 0.f, 0.f, 0.f}, {0.f, 0.f, 0.f, 0.f},
                           {0.f, 0.f, 0.f, 0.f}, {0.f, 0.f, 0.f, 0.f}};
        int base = 0;
        for (; base + 8 <= clen; base += 8) {
            float4 w[8];
#pragma unroll
            for (int k = 0; k < 8; ++k)
                w[k] = *(const float4*)(W + (size_t)(i0 + base + k) * out_dim + j4);
#pragma unroll
            for (int k = 0; k < 8; ++k) {
#pragma unroll
                for (int s = 0; s < 4; ++s) {
                    float h = hlds[s][base + k];
                    acc[s][0] += h * w[k].x;
                    acc[s][1] += h * w[k].y;
                    acc[s][2] += h * w[k].z;
                    acc[s][3] += h * w[k].w;
                }
            }
        }
        for (; base < clen; ++base) {
            float4 w = *(const float4*)(W + (size_t)(i0 + base) * out_dim + j4);
#pragma unroll
            for (int s = 0; s < 4; ++s) {
                float h = hlds[s][base];
                acc[s][0] += h * w.x;
                acc[s][1] += h * w.y;
                acc[s][2] += h * w.z;
                acc[s][3] += h * w.w;
            }
        }
#pragma unroll
        for (int s = 0; s < 4; ++s) {
            float4 o = make_float4(acc[s][0], acc[s][1], acc[s][2], acc[s][3]);
            *(float4*)(out_part + ((size_t)p * 4 + s) * out_dim + j4) = o;
        }
    }
}

// Layer 7 (1000 -> 1): per-block partial dot over an i-chunk.
__global__ __launch_bounds__(256) void layer7_partial(const float* __restrict__ W7,
                                                      const float* __restrict__ part6,
                                                      const float* __restrict__ b6,
                                                      float* __restrict__ part7,
                                                      const int in_dim, const int chunk,
                                                      const int prev_ns) {
    __shared__ float hl[4][32];
    __shared__ float wl[32];
    const int p = blockIdx.x;
    const int i0 = p * chunk;
    const int clen = min(chunk, in_dim - i0);
    const int tid = threadIdx.x;

    // parallel staging with batch-8 loads
    {
        const int idx = tid >> 2;
        const int s = tid & 3;
        if (idx < clen) {
            const int i = i0 + idx;
            float a = b6[i];
            int pp0 = 0;
            for (; pp0 + 8 <= prev_ns; pp0 += 8) {
                float t[8];
#pragma unroll
                for (int k = 0; k < 8; ++k)
                    t[k] = part6[((size_t)(pp0 + k) * 4 + s) * in_dim + i];
#pragma unroll
                for (int k = 0; k < 8; ++k) a += t[k];
            }
            for (; pp0 < prev_ns; ++pp0)
                a += part6[((size_t)pp0 * 4 + s) * in_dim + i];
            hl[s][idx] = fmaxf(a, 0.0f);
            if (s == 0) wl[idx] = W7[i];
        }
    }
    __syncthreads();

    if (tid < 4) {
        float acc = 0.0f;
        for (int idx = 0; idx < clen; ++idx) acc += hl[tid][idx] * wl[idx];
        part7[p * 4 + tid] = acc;
    }
}

__global__ void final_kernel(const float* __restrict__ part7,
                             const float* __restrict__ b7,
                             float* __restrict__ out, const int ns) {
    const int s = threadIdx.x;
    if (s < 4) {
        float acc = b7[0];
        for (int p = 0; p < ns; ++p) acc += part7[p * 4 + s];
        out[s] = acc;
    }
}

// ---------------------------------------------------------------------------
extern "C" void kernel_launch(void* const* d_in, const int* in_sizes, int n_in,
                              void* d_out, int out_size, void* d_ws, size_t ws_size,
                              hipStream_t stream) {
    const float* pv    = (const float*)d_in[0];
    const float* qv    = (const float*)d_in[1];
    const float* plen  = (const float*)d_in[2];
    const float* qlen  = (const float*)d_in[3];
    const float* mask  = (const float*)d_in[4];
    const float* gamma = (const float*)d_in[5];
    const float* beta  = (const float*)d_in[6];
    const float* W[7];
    const float* b[7];
    for (int i = 0; i < 7; ++i) {
        W[i] = (const float*)d_in[7 + 2 * i];
        b[i] = (const float*)d_in[8 + 2 * i];
    }

    float* ws = (float*)d_ws;
    float* sums  = ws;                                  // 2*4512*104 = 938496 floats
    float* feats = ws + 938496;                         // 4512 floats
    float* partA = ws + 943008;                         // 32*4*1000 = 128000 floats (16B-aligned)
    float* partB = partA + 128000;                      // 128000 floats
    float* part7 = partB + 128000;                      // 128 floats
    float* out = (float*)d_out;

    // 1) moments: pair-split body, 4 waves/block (one wave per sf task)
    moments_kernel<<<dim3(1128, 2), 256, 0, stream>>>(pv, qv, sums);
    // 2) symmetric KL -> feats: 32 sf per block, p/q lane-split, LDS factors
    kl_kernel<<<dim3(141), 64, 0, stream>>>(sums, plen, qlen, mask, feats);
    // 3) MLP. L1 fuses BatchNorm; each layer fuses prev partial-reduce+bias+relu.
    layer_partial<<<32, 256, 0, stream>>>(W[0], 1128, 1000, 36, nullptr, 0, nullptr,
                                          feats, gamma, beta, partA);
    layer_partial<<<32, 256, 0, stream>>>(W[1], 1000, 1000, 32, partA, 32, b[0],
                                          nullptr, nullptr, nullptr, partB);
    layer_partial<<<32, 256, 0, stream>>>(W[2], 1000, 1000, 32, partB, 32, b[1],
                                          nullptr, nullptr, nullptr, partA);
    layer_partial<<<32, 256, 0, stream>>>(W[3], 1000, 1000, 32, partA, 32, b[2],
                                          nullptr, nullptr, nullptr, partB);
    layer_partial<<<32, 256, 0, stream>>>(W[4], 1000, 1000, 32, partB, 32, b[3],
                                          nullptr, nullptr, nullptr, partA);
    layer_partial<<<32, 256, 0, stream>>>(W[5], 1000, 1000, 32, partA, 32, b[4],
                                          nullptr, nullptr, nullptr, partB);
    layer7_partial<<<32, 256, 0, stream>>>(W[6], partB, b[5], part7, 1000, 32, 32);
    final_kernel<<<1, 64, 0, stream>>>(part7, b[6], out, 32);
}